// Round 10
// baseline (147.738 us; speedup 1.0000x reference)
//
#include <hip/hip_runtime.h>
#include <hip/hip_bf16.h>

#define L_SEQ 1024
#define DI    5120
#define DS    16
#define DR    160
#define NE    192      // DR + 2*DS
#define NC    32       // scan chunks
#define CL    32       // chunk length = L_SEQ/NC
#define SPLITK 16
#define KSPLIT (DI / SPLITK)   // 320
#define BK    64
#define LOG2E 1.44269504088896340736f

// workspace layout (bytes); ws ~256MiB, we use ~80MB
#define OFF_P     0
#define SZ_P      (SPLITK * L_SEQ * NE * 4)   // 12,582,912
#define OFF_XDBL  (OFF_P + SZ_P)
#define SZ_XDBL   (L_SEQ * NE * 4)            // 786,432
#define OFF_DELTA (OFF_XDBL + SZ_XDBL)
#define SZ_DELTA  (L_SEQ * DI * 4)            // 20,971,520
#define OFF_HEND  (OFF_DELTA + SZ_DELTA)
#define SZ_H      (NC * DS * DI * 4)          // 10,485,760
#define OFF_APROD (OFF_HEND + SZ_H)
#define WS_END0   (OFF_APROD + SZ_H)
// dtw/xdbl bf16 hi/lo planes live inside HEND region (dead until k_scan1):
#define OFF_WH    OFF_HEND                     // dtw hi: 1,638,400
#define OFF_WL    (OFF_WH + 1638400)           // dtw lo
#define OFF_XH    (OFF_WL + 1638400)           // xdbl hi: 393,216
#define OFF_XL    (OFF_XH + 393216)            // xdbl lo (total 4.06MB < 10.49MB)
// x / xw planes: fresh space after aprod
#define OFF_XPH   WS_END0                      // x hi: 10,485,760
#define OFF_XPL   (OFF_XPH + 10485760)
#define OFF_XWH   (OFF_XPL + 10485760)         // xw hi: 1,966,080
#define OFF_XWL   (OFF_XWH + 1966080)

typedef short s16x8 __attribute__((ext_vector_type(8)));   // 8 bf16 in 4 VGPRs
typedef float f32x4 __attribute__((ext_vector_type(4)));

__device__ __forceinline__ unsigned short bf_rn(float f) {
  unsigned u = __float_as_uint(f);
  u += 0x7FFFu + ((u >> 16) & 1u);      // round-to-nearest-even
  return (unsigned short)(u >> 16);
}
__device__ __forceinline__ void split_hilo(float f, unsigned short& h, unsigned short& l) {
  h = bf_rn(f);
  float hf = __uint_as_float(((unsigned)h) << 16);
  l = bf_rn(f - hf);
}

// ---------------- generic cvt: f32 -> bf16 hi/lo planes, 4 elems/thread
__global__ __launch_bounds__(256) void k_cvt(const float* __restrict__ src,
                                             unsigned short* __restrict__ hi,
                                             unsigned short* __restrict__ lo,
                                             int n4) {
  int i = blockIdx.x * 256 + threadIdx.x;
  if (i >= n4) return;
  int i4 = i * 4;
  float4 v = *(const float4*)&src[i4];
  float f[4] = {v.x, v.y, v.z, v.w};
  ushort4 h, l;
  unsigned short hh, ll;
  split_hilo(f[0], hh, ll); h.x = hh; l.x = ll;
  split_hilo(f[1], hh, ll); h.y = hh; l.y = ll;
  split_hilo(f[2], hh, ll); h.z = hh; l.z = ll;
  split_hilo(f[3], hh, ll); h.w = hh; l.w = ll;
  *(ushort4*)&hi[i4] = h;
  *(ushort4*)&lo[i4] = l;
}

// ---------------- GEMM1 (MFMA, preconverted planes): part[z][l][e] = x[l,:]·xw[e,:]
#define AST2 72   // LDS row stride in shorts (144B -> 2-way bank aliasing, free)
__global__ __launch_bounds__(256) void k_xdbl_mfma2(const unsigned short* __restrict__ xph,
                                                    const unsigned short* __restrict__ xpl,
                                                    const unsigned short* __restrict__ wxh,
                                                    const unsigned short* __restrict__ wxl,
                                                    float* __restrict__ part) {
  __shared__ unsigned short sAh[64 * AST2];
  __shared__ unsigned short sAl[64 * AST2];
  const int tid  = threadIdx.x;
  const int lane = tid & 63;
  const int w    = tid >> 6;            // 0..3
  const int wl_  = w >> 1;              // l-subtile 0..1
  const int we   = w & 1;               // e-subtile 0..1
  const int l0   = blockIdx.y * 64;
  const int e0   = blockIdx.x * 64 + we * 32;
  const int kb   = blockIdx.z * KSPLIT;
  const int rc   = lane & 15;
  const int kg   = (lane >> 4) * 8;

  f32x4 acc[2][2] = {};
  for (int k0 = 0; k0 < KSPLIT; k0 += BK) {
    __syncthreads();
    for (int idx = tid; idx < 64 * 8; idx += 256) {      // 64 rows x 8 chunks(8sh)
      int r = idx >> 3, c8 = (idx & 7) * 8;
      *(s16x8*)&sAh[r * AST2 + c8] = *(const s16x8*)&xph[(size_t)(l0 + r) * DI + kb + k0 + c8];
      *(s16x8*)&sAl[r * AST2 + c8] = *(const s16x8*)&xpl[(size_t)(l0 + r) * DI + kb + k0 + c8];
    }
    __syncthreads();
#pragma unroll
    for (int ks = 0; ks < BK; ks += 32) {
      s16x8 ah[2], al[2], bh[2], bl[2];
#pragma unroll
      for (int mf = 0; mf < 2; ++mf) {
        int row = wl_ * 32 + mf * 16 + rc;
        ah[mf] = *(const s16x8*)&sAh[row * AST2 + ks + kg];
        al[mf] = *(const s16x8*)&sAl[row * AST2 + ks + kg];
      }
#pragma unroll
      for (int nf = 0; nf < 2; ++nf) {
        size_t e = e0 + nf * 16 + rc;
        bh[nf] = *(const s16x8*)&wxh[e * DI + kb + k0 + ks + kg];
        bl[nf] = *(const s16x8*)&wxl[e * DI + kb + k0 + ks + kg];
      }
#pragma unroll
      for (int mf = 0; mf < 2; ++mf)
#pragma unroll
        for (int nf = 0; nf < 2; ++nf) {
          acc[mf][nf] = __builtin_amdgcn_mfma_f32_16x16x32_bf16(ah[mf], bh[nf], acc[mf][nf], 0, 0, 0);
          acc[mf][nf] = __builtin_amdgcn_mfma_f32_16x16x32_bf16(ah[mf], bl[nf], acc[mf][nf], 0, 0, 0);
          acc[mf][nf] = __builtin_amdgcn_mfma_f32_16x16x32_bf16(al[mf], bh[nf], acc[mf][nf], 0, 0, 0);
        }
    }
  }
#pragma unroll
  for (int mf = 0; mf < 2; ++mf)
#pragma unroll
    for (int nf = 0; nf < 2; ++nf)
#pragma unroll
      for (int r = 0; r < 4; ++r) {
        int l = l0 + wl_ * 32 + mf * 16 + (lane >> 4) * 4 + r;  // C/D: row=(lane>>4)*4+reg
        int e = e0 + nf * 16 + rc;                              //      col=lane&15
        part[((size_t)blockIdx.z * L_SEQ + l) * NE + e] = acc[mf][nf][r];
      }
}

// ---------------- reduce split-K partials; also emit xdbl bf16 hi/lo planes
__global__ __launch_bounds__(256) void k_xdbl_reduce(const float* __restrict__ part,
                                                     float* __restrict__ xdbl,
                                                     unsigned short* __restrict__ xh,
                                                     unsigned short* __restrict__ xl) {
  int i4 = (blockIdx.x * 256 + threadIdx.x) * 4;   // grid=192
  float4 s = {0.f, 0.f, 0.f, 0.f};
#pragma unroll
  for (int z = 0; z < SPLITK; ++z) {
    float4 p = *(const float4*)&part[(size_t)z * L_SEQ * NE + i4];
    s.x += p.x; s.y += p.y; s.z += p.z; s.w += p.w;
  }
  *(float4*)&xdbl[i4] = s;
  float f[4] = {s.x, s.y, s.z, s.w};
  ushort4 h, l;
  unsigned short hh, ll;
  split_hilo(f[0], hh, ll); h.x = hh; l.x = ll;
  split_hilo(f[1], hh, ll); h.y = hh; l.y = ll;
  split_hilo(f[2], hh, ll); h.z = hh; l.z = ll;
  split_hilo(f[3], hh, ll); h.w = hh; l.w = ll;
  *(ushort4*)&xh[i4] = h;
  *(ushort4*)&xl[i4] = l;
}

// ---------------- GEMM2 (MFMA, preconverted bf16): delta = softplus(dt·dtw^T + b)
#define AST 168
__global__ __launch_bounds__(512) void k_delta_mfma2(const unsigned short* __restrict__ xh,
                                                     const unsigned short* __restrict__ xl,
                                                     const unsigned short* __restrict__ wh,
                                                     const unsigned short* __restrict__ wlo,
                                                     const float* __restrict__ dtb,
                                                     float* __restrict__ delta) {
  __shared__ unsigned short sAh[64 * AST];
  __shared__ unsigned short sAl[64 * AST];
  const int tid  = threadIdx.x;
  const int lane = tid & 63;
  const int w    = tid >> 6;
  const int wl_  = w >> 2;
  const int wd   = w & 3;
  const int l0   = blockIdx.y * 64;
  const int d0   = blockIdx.x * 128 + wd * 32;
  const int rc   = lane & 15;
  const int kg   = (lane >> 4) * 8;

  for (int idx = tid; idx < 64 * 20; idx += 512) {
    int r = idx / 20, c8 = (idx % 20) * 8;
    *(s16x8*)&sAh[r * AST + c8] = *(const s16x8*)&xh[(size_t)(l0 + r) * NE + c8];
    *(s16x8*)&sAl[r * AST + c8] = *(const s16x8*)&xl[(size_t)(l0 + r) * NE + c8];
  }
  __syncthreads();

  f32x4 acc[2][2] = {};
#pragma unroll
  for (int k0 = 0; k0 < DR; k0 += 32) {
    s16x8 ah[2], al[2], bh[2], bl[2];
#pragma unroll
    for (int mf = 0; mf < 2; ++mf) {
      int row = wl_ * 32 + mf * 16 + rc;
      ah[mf] = *(const s16x8*)&sAh[row * AST + k0 + kg];
      al[mf] = *(const s16x8*)&sAl[row * AST + k0 + kg];
    }
#pragma unroll
    for (int nf = 0; nf < 2; ++nf) {
      size_t d = d0 + nf * 16 + rc;
      bh[nf] = *(const s16x8*)&wh[d * DR + k0 + kg];
      bl[nf] = *(const s16x8*)&wlo[d * DR + k0 + kg];
    }
#pragma unroll
    for (int mf = 0; mf < 2; ++mf)
#pragma unroll
      for (int nf = 0; nf < 2; ++nf) {
        acc[mf][nf] = __builtin_amdgcn_mfma_f32_16x16x32_bf16(ah[mf], bh[nf], acc[mf][nf], 0, 0, 0);
        acc[mf][nf] = __builtin_amdgcn_mfma_f32_16x16x32_bf16(ah[mf], bl[nf], acc[mf][nf], 0, 0, 0);
        acc[mf][nf] = __builtin_amdgcn_mfma_f32_16x16x32_bf16(al[mf], bh[nf], acc[mf][nf], 0, 0, 0);
      }
  }
#pragma unroll
  for (int nf = 0; nf < 2; ++nf) {
    int d = d0 + nf * 16 + rc;
    float bias = dtb[d];
#pragma unroll
    for (int mf = 0; mf < 2; ++mf)
#pragma unroll
      for (int r = 0; r < 4; ++r) {
        int l = l0 + wl_ * 32 + mf * 16 + (lane >> 4) * 4 + r;
        float z = acc[mf][nf][r] + bias;
        float sp = fmaxf(z, 0.f) + __logf(1.f + __expf(-fabsf(z)));
        delta[(size_t)l * DI + d] = sp;
      }
  }
}

// ---------------- scan pass 1: 16 n per thread, 64 contiguous d per wave, PF=4
__global__ __launch_bounds__(256) void k_scan1(const float* __restrict__ x,
                                               const float* __restrict__ delta,
                                               const float* __restrict__ xdbl,
                                               const float* __restrict__ A_log,
                                               float* __restrict__ hend,
                                               float* __restrict__ aprod) {
  const int d = blockIdx.x * 256 + threadIdx.x;
  const int c = blockIdx.y;
  __shared__ __align__(16) float sB[CL][DS];
  for (int i = threadIdx.x; i < CL * DS; i += 256) {
    int t = i >> 4, n = i & 15;
    sB[t][n] = xdbl[(size_t)(c * CL + t) * NE + DR + n];
  }
  __syncthreads();
  float aL[DS], h[DS];
#pragma unroll
  for (int q4 = 0; q4 < DS; q4 += 4) {
    float4 av = *(const float4*)&A_log[(size_t)d * DS + q4];
    aL[q4 + 0] = -__expf(av.x) * LOG2E;
    aL[q4 + 1] = -__expf(av.y) * LOG2E;
    aL[q4 + 2] = -__expf(av.z) * LOG2E;
    aL[q4 + 3] = -__expf(av.w) * LOG2E;
  }
#pragma unroll
  for (int q = 0; q < DS; ++q) h[q] = 0.f;
  float sdl = 0.f;

  const float* dp = &delta[(size_t)(c * CL) * DI + d];
  const float* xp = &x[(size_t)(c * CL) * DI + d];
  float dlb[4], xvb[4];
#pragma unroll
  for (int j = 0; j < 4; ++j) { dlb[j] = dp[(size_t)j * DI]; xvb[j] = xp[(size_t)j * DI]; }
  for (int tt = 0; tt < CL; tt += 4) {
    bool pf = (tt + 4 < CL);
#pragma unroll
    for (int j = 0; j < 4; ++j) {
      float dl = dlb[j], xv = xvb[j];
      if (pf) { int tn = tt + 4 + j; dlb[j] = dp[(size_t)tn * DI]; xvb[j] = xp[(size_t)tn * DI]; }
      float du = dl * xv;
      sdl += dl;
#pragma unroll
      for (int q4 = 0; q4 < DS; q4 += 4) {
        float4 b4 = *(const float4*)&sB[tt + j][q4];
        float bb[4] = {b4.x, b4.y, b4.z, b4.w};
#pragma unroll
        for (int u = 0; u < 4; ++u) {
          float dA = exp2f(dl * aL[q4 + u]);
          h[q4 + u] = dA * h[q4 + u] + du * bb[u];
        }
      }
    }
  }
#pragma unroll
  for (int q = 0; q < DS; ++q) {
    hend[(size_t)(c * DS + q) * DI + d] = h[q];
    aprod[(size_t)(c * DS + q) * DI + d] = exp2f(aL[q] * sdl);
  }
}

// ---------------- scan pass 2: load-all-then-carry (in-place -> hstart)
__global__ __launch_bounds__(256) void k_scan2(float* __restrict__ hend,
                                               const float* __restrict__ aprod) {
  int i = blockIdx.x * 256 + threadIdx.x;   // 81920 total, grid=320
  float ap[NC], hv[NC];
#pragma unroll
  for (int c = 0; c < NC; ++c) {
    size_t idx = (size_t)c * DS * DI + i;
    ap[c] = aprod[idx];
    hv[c] = hend[idx];
  }
  float carry = 0.f;
#pragma unroll
  for (int c = 0; c < NC; ++c) {
    size_t idx = (size_t)c * DS * DI + i;
    hend[idx] = carry;
    carry = ap[c] * carry + hv[c];
  }
}

// ---------------- scan pass 3: 16 n per thread, 64 contiguous d per wave, PF=4
__global__ __launch_bounds__(256) void k_scan3(const float* __restrict__ x,
                                               const float* __restrict__ delta,
                                               const float* __restrict__ xdbl,
                                               const float* __restrict__ A_log,
                                               const float* __restrict__ Dvec,
                                               const float* __restrict__ hstart,
                                               float* __restrict__ out) {
  const int d = blockIdx.x * 256 + threadIdx.x;
  const int c = blockIdx.y;
  __shared__ __align__(16) float sB[CL][DS];
  __shared__ __align__(16) float sC[CL][DS];
  for (int i = threadIdx.x; i < CL * DS; i += 256) {
    int t = i >> 4, n = i & 15;
    sB[t][n] = xdbl[(size_t)(c * CL + t) * NE + DR + n];
    sC[t][n] = xdbl[(size_t)(c * CL + t) * NE + DR + DS + n];
  }
  __syncthreads();
  float aL[DS], h[DS];
#pragma unroll
  for (int q4 = 0; q4 < DS; q4 += 4) {
    float4 av = *(const float4*)&A_log[(size_t)d * DS + q4];
    aL[q4 + 0] = -__expf(av.x) * LOG2E;
    aL[q4 + 1] = -__expf(av.y) * LOG2E;
    aL[q4 + 2] = -__expf(av.z) * LOG2E;
    aL[q4 + 3] = -__expf(av.w) * LOG2E;
  }
#pragma unroll
  for (int q = 0; q < DS; ++q)
    h[q] = hstart[(size_t)(c * DS + q) * DI + d];
  const float Dv = Dvec[d];

  const float* dp = &delta[(size_t)(c * CL) * DI + d];
  const float* xp = &x[(size_t)(c * CL) * DI + d];
  float* op = &out[(size_t)(c * CL) * DI + d];
  float dlb[4], xvb[4];
#pragma unroll
  for (int j = 0; j < 4; ++j) { dlb[j] = dp[(size_t)j * DI]; xvb[j] = xp[(size_t)j * DI]; }
  for (int tt = 0; tt < CL; tt += 4) {
    bool pf = (tt + 4 < CL);
#pragma unroll
    for (int j = 0; j < 4; ++j) {
      float dl = dlb[j], xv = xvb[j];
      if (pf) { int tn = tt + 4 + j; dlb[j] = dp[(size_t)tn * DI]; xvb[j] = xp[(size_t)tn * DI]; }
      float du = dl * xv;
      float yp[4] = {0.f, 0.f, 0.f, 0.f};
#pragma unroll
      for (int q4 = 0; q4 < DS; q4 += 4) {
        float4 b4 = *(const float4*)&sB[tt + j][q4];
        float4 c4 = *(const float4*)&sC[tt + j][q4];
        float bb[4] = {b4.x, b4.y, b4.z, b4.w};
        float cc[4] = {c4.x, c4.y, c4.z, c4.w};
#pragma unroll
        for (int u = 0; u < 4; ++u) {
          float dA = exp2f(dl * aL[q4 + u]);
          h[q4 + u] = dA * h[q4 + u] + du * bb[u];
          yp[u] += h[q4 + u] * cc[u];
        }
      }
      float y = (yp[0] + yp[1]) + (yp[2] + yp[3]);
      op[(size_t)(tt + j) * DI] = fmaf(xv, Dv, y);
    }
  }
}

extern "C" void kernel_launch(void* const* d_in, const int* in_sizes, int n_in,
                              void* d_out, int out_size, void* d_ws, size_t ws_size,
                              hipStream_t stream) {
  const float* x     = (const float*)d_in[0];
  const float* A_log = (const float*)d_in[1];
  const float* Dvec  = (const float*)d_in[2];
  const float* xw    = (const float*)d_in[3];
  const float* dtw   = (const float*)d_in[4];
  const float* dtb   = (const float*)d_in[5];
  float* out = (float*)d_out;

  char* ws = (char*)d_ws;
  float* part  = (float*)(ws + OFF_P);
  float* xdbl  = (float*)(ws + OFF_XDBL);
  float* delta = (float*)(ws + OFF_DELTA);
  float* hend  = (float*)(ws + OFF_HEND);
  float* aprod = (float*)(ws + OFF_APROD);
  unsigned short* wh  = (unsigned short*)(ws + OFF_WH);
  unsigned short* wl  = (unsigned short*)(ws + OFF_WL);
  unsigned short* xh  = (unsigned short*)(ws + OFF_XH);
  unsigned short* xl  = (unsigned short*)(ws + OFF_XL);
  unsigned short* xph = (unsigned short*)(ws + OFF_XPH);
  unsigned short* xpl = (unsigned short*)(ws + OFF_XPL);
  unsigned short* wxh = (unsigned short*)(ws + OFF_XWH);
  unsigned short* wxl = (unsigned short*)(ws + OFF_XWL);

  k_cvt<<<5120, 256, 0, stream>>>(x, xph, xpl, L_SEQ * DI / 4);      // x planes
  k_cvt<<<960, 256, 0, stream>>>(xw, wxh, wxl, NE * DI / 4);         // xw planes
  k_cvt<<<800, 256, 0, stream>>>(dtw, wh, wl, DI * DR / 4);          // dtw planes
  k_xdbl_mfma2<<<dim3(3, 16, SPLITK), 256, 0, stream>>>(xph, xpl, wxh, wxl, part);
  k_xdbl_reduce<<<192, 256, 0, stream>>>(part, xdbl, xh, xl);
  k_delta_mfma2<<<dim3(40, 16), 512, 0, stream>>>(xh, xl, wh, wl, dtb, delta);
  k_scan1<<<dim3(20, NC), 256, 0, stream>>>(x, delta, xdbl, A_log, hend, aprod);
  k_scan2<<<320, 256, 0, stream>>>(hend, aprod);
  k_scan3<<<dim3(20, NC), 256, 0, stream>>>(x, delta, xdbl, A_log, Dvec, hend, out);
}

// Round 12
// 131.051 us; speedup vs baseline: 1.1273x; 1.1273x over previous
//
#include <hip/hip_runtime.h>
#include <hip/hip_bf16.h>
#include <hip/hip_cooperative_groups.h>

namespace cg = cooperative_groups;

#define L_SEQ 1024
#define DI    5120
#define DS    16
#define DR    160
#define NE    192      // DR + 2*DS
#define NC    32       // scan chunks
#define CL    32       // chunk length = L_SEQ/NC
#define SPLITK 16
#define KSPLIT (DI / SPLITK)   // 320
#define BK    64
#define LOG2E 1.44269504088896340736f

// workspace layout (bytes); ws ~256MiB observed, we use ~117MB
#define OFF_P     0
#define SZ_P      (SPLITK * L_SEQ * NE * 4)
#define OFF_XDBL  (OFF_P + SZ_P)
#define SZ_XDBL   (L_SEQ * NE * 4)
#define OFF_DELTA (OFF_XDBL + SZ_XDBL)       // region kept reserved (unused now)
#define SZ_DELTA  (L_SEQ * DI * 4)
#define OFF_HEND  (OFF_DELTA + SZ_DELTA)
#define SZ_H      (NC * DS * DI * 4)          // 10,485,760
#define OFF_APROD (OFF_HEND + SZ_H)
#define WS_END0   (OFF_APROD + SZ_H)
// dtw/xdbl bf16 hi/lo planes inside HEND region (dead until scans):
#define OFF_WH    OFF_HEND
#define OFF_WL    (OFF_WH + 1638400)
#define OFF_XH    (OFF_WL + 1638400)
#define OFF_XL    (OFF_XH + 393216)
// x / xw planes after aprod
#define OFF_XPH   WS_END0
#define OFF_XPL   (OFF_XPH + 10485760)
#define OFF_XWH   (OFF_XPL + 10485760)
#define OFF_XWL   (OFF_XWH + 1966080)
// interleaved (delta,x) float2 buffer
#define OFF_ZB    (OFF_XWL + 1966080)         // 41,943,040 B

typedef short s16x8 __attribute__((ext_vector_type(8)));
typedef float f32x4 __attribute__((ext_vector_type(4)));

__device__ __forceinline__ unsigned short bf_rn(float f) {
  unsigned u = __float_as_uint(f);
  u += 0x7FFFu + ((u >> 16) & 1u);
  return (unsigned short)(u >> 16);
}
__device__ __forceinline__ void split_hilo(float f, unsigned short& h, unsigned short& l) {
  h = bf_rn(f);
  float hf = __uint_as_float(((unsigned)h) << 16);
  l = bf_rn(f - hf);
}

// ---------------- generic cvt: f32 -> bf16 hi/lo planes
__global__ __launch_bounds__(256) void k_cvt(const float* __restrict__ src,
                                             unsigned short* __restrict__ hi,
                                             unsigned short* __restrict__ lo,
                                             int n4) {
  int i = blockIdx.x * 256 + threadIdx.x;
  if (i >= n4) return;
  int i4 = i * 4;
  float4 v = *(const float4*)&src[i4];
  float f[4] = {v.x, v.y, v.z, v.w};
  ushort4 h, l;
  unsigned short hh, ll;
  split_hilo(f[0], hh, ll); h.x = hh; l.x = ll;
  split_hilo(f[1], hh, ll); h.y = hh; l.y = ll;
  split_hilo(f[2], hh, ll); h.z = hh; l.z = ll;
  split_hilo(f[3], hh, ll); h.w = hh; l.w = ll;
  *(ushort4*)&hi[i4] = h;
  *(ushort4*)&lo[i4] = l;
}

// ---------------- GEMM1 (MFMA, preconverted planes)
#define AST2 72
__global__ __launch_bounds__(256) void k_xdbl_mfma2(const unsigned short* __restrict__ xph,
                                                    const unsigned short* __restrict__ xpl,
                                                    const unsigned short* __restrict__ wxh,
                                                    const unsigned short* __restrict__ wxl,
                                                    float* __restrict__ part) {
  __shared__ unsigned short sAh[64 * AST2];
  __shared__ unsigned short sAl[64 * AST2];
  const int tid  = threadIdx.x;
  const int lane = tid & 63;
  const int w    = tid >> 6;
  const int wl_  = w >> 1;
  const int we   = w & 1;
  const int l0   = blockIdx.y * 64;
  const int e0   = blockIdx.x * 64 + we * 32;
  const int kb   = blockIdx.z * KSPLIT;
  const int rc   = lane & 15;
  const int kg   = (lane >> 4) * 8;

  f32x4 acc[2][2] = {};
  for (int k0 = 0; k0 < KSPLIT; k0 += BK) {
    __syncthreads();
    for (int idx = tid; idx < 64 * 8; idx += 256) {
      int r = idx >> 3, c8 = (idx & 7) * 8;
      *(s16x8*)&sAh[r * AST2 + c8] = *(const s16x8*)&xph[(size_t)(l0 + r) * DI + kb + k0 + c8];
      *(s16x8*)&sAl[r * AST2 + c8] = *(const s16x8*)&xpl[(size_t)(l0 + r) * DI + kb + k0 + c8];
    }
    __syncthreads();
#pragma unroll
    for (int ks = 0; ks < BK; ks += 32) {
      s16x8 ah[2], al[2], bh[2], bl[2];
#pragma unroll
      for (int mf = 0; mf < 2; ++mf) {
        int row = wl_ * 32 + mf * 16 + rc;
        ah[mf] = *(const s16x8*)&sAh[row * AST2 + ks + kg];
        al[mf] = *(const s16x8*)&sAl[row * AST2 + ks + kg];
      }
#pragma unroll
      for (int nf = 0; nf < 2; ++nf) {
        size_t e = e0 + nf * 16 + rc;
        bh[nf] = *(const s16x8*)&wxh[e * DI + kb + k0 + ks + kg];
        bl[nf] = *(const s16x8*)&wxl[e * DI + kb + k0 + ks + kg];
      }
#pragma unroll
      for (int mf = 0; mf < 2; ++mf)
#pragma unroll
        for (int nf = 0; nf < 2; ++nf) {
          acc[mf][nf] = __builtin_amdgcn_mfma_f32_16x16x32_bf16(ah[mf], bh[nf], acc[mf][nf], 0, 0, 0);
          acc[mf][nf] = __builtin_amdgcn_mfma_f32_16x16x32_bf16(ah[mf], bl[nf], acc[mf][nf], 0, 0, 0);
          acc[mf][nf] = __builtin_amdgcn_mfma_f32_16x16x32_bf16(al[mf], bh[nf], acc[mf][nf], 0, 0, 0);
        }
    }
  }
#pragma unroll
  for (int mf = 0; mf < 2; ++mf)
#pragma unroll
    for (int nf = 0; nf < 2; ++nf)
#pragma unroll
      for (int r = 0; r < 4; ++r) {
        int l = l0 + wl_ * 32 + mf * 16 + (lane >> 4) * 4 + r;
        int e = e0 + nf * 16 + rc;
        part[((size_t)blockIdx.z * L_SEQ + l) * NE + e] = acc[mf][nf][r];
      }
}

// ---------------- reduce split-K partials; emit xdbl + bf16 planes
__global__ __launch_bounds__(256) void k_xdbl_reduce(const float* __restrict__ part,
                                                     float* __restrict__ xdbl,
                                                     unsigned short* __restrict__ xh,
                                                     unsigned short* __restrict__ xl) {
  int i4 = (blockIdx.x * 256 + threadIdx.x) * 4;   // grid=192
  float4 s = {0.f, 0.f, 0.f, 0.f};
#pragma unroll
  for (int z = 0; z < SPLITK; ++z) {
    float4 p = *(const float4*)&part[(size_t)z * L_SEQ * NE + i4];
    s.x += p.x; s.y += p.y; s.z += p.z; s.w += p.w;
  }
  *(float4*)&xdbl[i4] = s;
  float f[4] = {s.x, s.y, s.z, s.w};
  ushort4 h, l;
  unsigned short hh, ll;
  split_hilo(f[0], hh, ll); h.x = hh; l.x = ll;
  split_hilo(f[1], hh, ll); h.y = hh; l.y = ll;
  split_hilo(f[2], hh, ll); h.z = hh; l.z = ll;
  split_hilo(f[3], hh, ll); h.w = hh; l.w = ll;
  *(ushort4*)&xh[i4] = h;
  *(ushort4*)&xl[i4] = l;
}

// ---------------- GEMM2 (MFMA): writes interleaved zbuf[l][d] = (softplus, x)
#define AST 168
__global__ __launch_bounds__(512) void k_delta_mfma2(const unsigned short* __restrict__ xh,
                                                     const unsigned short* __restrict__ xl,
                                                     const unsigned short* __restrict__ wh,
                                                     const unsigned short* __restrict__ wlo,
                                                     const float* __restrict__ dtb,
                                                     const float* __restrict__ x,
                                                     float2* __restrict__ zbuf) {
  __shared__ unsigned short sAh[64 * AST];
  __shared__ unsigned short sAl[64 * AST];
  const int tid  = threadIdx.x;
  const int lane = tid & 63;
  const int w    = tid >> 6;
  const int wl_  = w >> 2;
  const int wd   = w & 3;
  const int l0   = blockIdx.y * 64;
  const int d0   = blockIdx.x * 128 + wd * 32;
  const int rc   = lane & 15;
  const int kg   = (lane >> 4) * 8;

  for (int idx = tid; idx < 64 * 20; idx += 512) {
    int r = idx / 20, c8 = (idx % 20) * 8;
    *(s16x8*)&sAh[r * AST + c8] = *(const s16x8*)&xh[(size_t)(l0 + r) * NE + c8];
    *(s16x8*)&sAl[r * AST + c8] = *(const s16x8*)&xl[(size_t)(l0 + r) * NE + c8];
  }
  __syncthreads();

  f32x4 acc[2][2] = {};
#pragma unroll
  for (int k0 = 0; k0 < DR; k0 += 32) {
    s16x8 ah[2], al[2], bh[2], bl[2];
#pragma unroll
    for (int mf = 0; mf < 2; ++mf) {
      int row = wl_ * 32 + mf * 16 + rc;
      ah[mf] = *(const s16x8*)&sAh[row * AST + k0 + kg];
      al[mf] = *(const s16x8*)&sAl[row * AST + k0 + kg];
    }
#pragma unroll
    for (int nf = 0; nf < 2; ++nf) {
      size_t d = d0 + nf * 16 + rc;
      bh[nf] = *(const s16x8*)&wh[d * DR + k0 + kg];
      bl[nf] = *(const s16x8*)&wlo[d * DR + k0 + kg];
    }
#pragma unroll
    for (int mf = 0; mf < 2; ++mf)
#pragma unroll
      for (int nf = 0; nf < 2; ++nf) {
        acc[mf][nf] = __builtin_amdgcn_mfma_f32_16x16x32_bf16(ah[mf], bh[nf], acc[mf][nf], 0, 0, 0);
        acc[mf][nf] = __builtin_amdgcn_mfma_f32_16x16x32_bf16(ah[mf], bl[nf], acc[mf][nf], 0, 0, 0);
        acc[mf][nf] = __builtin_amdgcn_mfma_f32_16x16x32_bf16(al[mf], bh[nf], acc[mf][nf], 0, 0, 0);
      }
  }
#pragma unroll
  for (int nf = 0; nf < 2; ++nf) {
    int d = d0 + nf * 16 + rc;
    float bias = dtb[d];
#pragma unroll
    for (int mf = 0; mf < 2; ++mf)
#pragma unroll
      for (int r = 0; r < 4; ++r) {
        int l = l0 + wl_ * 32 + mf * 16 + (lane >> 4) * 4 + r;
        float z = acc[mf][nf][r] + bias;
        float sp = fmaxf(z, 0.f) + __logf(1.f + __expf(-fabsf(z)));
        float xv = x[(size_t)l * DI + d];
        zbuf[(size_t)l * DI + d] = make_float2(sp, xv);
      }
  }
}

// ---------------- fused cooperative scan: 320 blocks x 512 thr, 2 grid syncs
__global__ __launch_bounds__(512, 4) void k_scan_fused2(const float2* __restrict__ zbuf,
                                                        const float* __restrict__ xdbl,
                                                        const float* __restrict__ A_log,
                                                        const float* __restrict__ Dvec,
                                                        float* __restrict__ hend,
                                                        float* __restrict__ aprod,
                                                        float* __restrict__ out) {
  const int tid = threadIdx.x;
  const int d   = blockIdx.x * 512 + tid;
  const int c   = blockIdx.y;
  __shared__ __align__(16) float sB[CL][DS];
  __shared__ __align__(16) float sC[CL][DS];
  __shared__ float sX[CL][512];                 // 64KB; total 69.6KB -> 2 blocks/CU

  {
    int i = tid;                                 // CL*DS = 512 = blockDim
    int t = i >> 4, n = i & 15;
    sB[t][n] = xdbl[(size_t)(c * CL + t) * NE + DR + n];
    sC[t][n] = xdbl[(size_t)(c * CL + t) * NE + DR + DS + n];
  }

  float aL[DS];
#pragma unroll
  for (int q4 = 0; q4 < DS; q4 += 4) {
    float4 av = *(const float4*)&A_log[(size_t)d * DS + q4];
    aL[q4 + 0] = -__expf(av.x) * LOG2E;
    aL[q4 + 1] = -__expf(av.y) * LOG2E;
    aL[q4 + 2] = -__expf(av.z) * LOG2E;
    aL[q4 + 3] = -__expf(av.w) * LOG2E;
  }

  const float2* zp = &zbuf[(size_t)(c * CL) * DI + d];
  float dl[CL];
#pragma unroll
  for (int j = 0; j < CL; ++j) {
    float2 z = zp[(size_t)j * DI];
    dl[j] = z.x;
    sX[j][tid] = z.y;
  }
  __syncthreads();   // sB/sC ready

  // phase 1: local scan from zero
  float h[DS];
#pragma unroll
  for (int q = 0; q < DS; ++q) h[q] = 0.f;
  float sdl = 0.f;
#pragma unroll
  for (int j = 0; j < CL; ++j) {
    float xv = sX[j][tid];
    float du = dl[j] * xv;
    sdl += dl[j];
#pragma unroll
    for (int q = 0; q < DS; ++q) {
      float dA = exp2f(dl[j] * aL[q]);
      h[q] = dA * h[q] + du * sB[j][q];
    }
  }
#pragma unroll
  for (int q = 0; q < DS; ++q) {
    hend[(size_t)(c * DS + q) * DI + d] = h[q];
    aprod[(size_t)(c * DS + q) * DI + d] = exp2f(aL[q] * sdl);
  }

  __threadfence();
  cg::this_grid().sync();

  // phase 2: linear cross-chunk carry (81920 chains, one per worker)
  {
    int fid = (blockIdx.y * gridDim.x + blockIdx.x) * 512 + tid;
    if (fid < DS * DI) {
      float carry = 0.f;
#pragma unroll 1
      for (int c2 = 0; c2 < NC; ++c2) {
        size_t idx = (size_t)c2 * DS * DI + fid;
        float ap = aprod[idx];
        float hv = hend[idx];
        hend[idx] = carry;                 // becomes hstart
        carry = ap * carry + hv;
      }
    }
  }
  __threadfence();
  cg::this_grid().sync();

  // phase 3: replay from carry-in; emit y
#pragma unroll
  for (int q = 0; q < DS; ++q)
    h[q] = hend[(size_t)(c * DS + q) * DI + d];
  const float Dv = Dvec[d];
  float* op = &out[(size_t)(c * CL) * DI + d];
#pragma unroll
  for (int j = 0; j < CL; ++j) {
    float dlj = dl[j];
    float xv = sX[j][tid];
    float du = dlj * xv;
    float yp[4] = {0.f, 0.f, 0.f, 0.f};
#pragma unroll
    for (int q4 = 0; q4 < DS; q4 += 4) {
#pragma unroll
      for (int u = 0; u < 4; ++u) {
        float dA = exp2f(dlj * aL[q4 + u]);
        h[q4 + u] = dA * h[q4 + u] + du * sB[j][q4 + u];
        yp[u] += h[q4 + u] * sC[j][q4 + u];
      }
    }
    float y = (yp[0] + yp[1]) + (yp[2] + yp[3]);
    op[(size_t)j * DI] = fmaf(xv, Dv, y);
  }
}

// ---------------- fallback 3-pass scans (R9 structure, zbuf float2 loads, NC=32)
__global__ __launch_bounds__(256) void k_scan1f(const float2* __restrict__ zbuf,
                                                const float* __restrict__ xdbl,
                                                const float* __restrict__ A_log,
                                                float* __restrict__ hend,
                                                float* __restrict__ aprod) {
  const int lane = threadIdx.x & 63;
  const int w    = threadIdx.x >> 6;
  const int d    = blockIdx.x * 64 + w * 16 + (lane & 15);
  const int ng   = lane >> 4;
  const int c    = blockIdx.y;
  __shared__ __align__(16) float sB[CL][DS];
  for (int i = threadIdx.x; i < CL * DS; i += 256) {
    int t = i >> 4, n = i & 15;
    sB[t][n] = xdbl[(size_t)(c * CL + t) * NE + DR + n];
  }
  __syncthreads();
  float4 av = *(const float4*)&A_log[(size_t)d * DS + ng * 4];
  float aL[4] = {-__expf(av.x) * LOG2E, -__expf(av.y) * LOG2E,
                 -__expf(av.z) * LOG2E, -__expf(av.w) * LOG2E};
  float h[4] = {0.f, 0.f, 0.f, 0.f};
  float sdl = 0.f;
  const float2* zp = &zbuf[(size_t)(c * CL) * DI + d];
  float2 zb[8];
#pragma unroll
  for (int j = 0; j < 8; ++j) zb[j] = zp[(size_t)j * DI];
  for (int tt = 0; tt < CL; tt += 8) {
#pragma unroll
    for (int j = 0; j < 8; ++j) {
      float dl = zb[j].x, xv = zb[j].y;
      int tn = tt + 8 + j;
      if (tn < CL) zb[j] = zp[(size_t)tn * DI];
      float du = dl * xv;
      sdl += dl;
      float4 b4 = *(const float4*)&sB[tt + j][ng * 4];
      float bb[4] = {b4.x, b4.y, b4.z, b4.w};
#pragma unroll
      for (int q = 0; q < 4; ++q) {
        float dA = exp2f(dl * aL[q]);
        h[q] = dA * h[q] + du * bb[q];
      }
    }
  }
#pragma unroll
  for (int q = 0; q < 4; ++q) {
    int n = ng * 4 + q;
    hend[(size_t)(c * DS + n) * DI + d] = h[q];
    aprod[(size_t)(c * DS + n) * DI + d] = exp2f(aL[q] * sdl);
  }
}

__global__ __launch_bounds__(256) void k_scan2f(float* __restrict__ hend,
                                                const float* __restrict__ aprod) {
  int i = blockIdx.x * 256 + threadIdx.x;   // 81920, grid=320
  float carry = 0.f;
#pragma unroll 1
  for (int c = 0; c < NC; ++c) {
    size_t idx = (size_t)c * DS * DI + i;
    float ap = aprod[idx];
    float hv = hend[idx];
    hend[idx] = carry;
    carry = ap * carry + hv;
  }
}

__global__ __launch_bounds__(256) void k_scan3f(const float2* __restrict__ zbuf,
                                                const float* __restrict__ xdbl,
                                                const float* __restrict__ A_log,
                                                const float* __restrict__ Dvec,
                                                const float* __restrict__ hstart,
                                                float* __restrict__ out) {
  const int lane = threadIdx.x & 63;
  const int w    = threadIdx.x >> 6;
  const int d    = blockIdx.x * 64 + w * 16 + (lane & 15);
  const int ng   = lane >> 4;
  const int c    = blockIdx.y;
  __shared__ __align__(16) float sB[CL][DS];
  __shared__ __align__(16) float sC[CL][DS];
  for (int i = threadIdx.x; i < CL * DS; i += 256) {
    int t = i >> 4, n = i & 15;
    sB[t][n] = xdbl[(size_t)(c * CL + t) * NE + DR + n];
    sC[t][n] = xdbl[(size_t)(c * CL + t) * NE + DR + DS + n];
  }
  __syncthreads();
  float4 av = *(const float4*)&A_log[(size_t)d * DS + ng * 4];
  float aL[4] = {-__expf(av.x) * LOG2E, -__expf(av.y) * LOG2E,
                 -__expf(av.z) * LOG2E, -__expf(av.w) * LOG2E};
  float h[4];
#pragma unroll
  for (int q = 0; q < 4; ++q)
    h[q] = hstart[(size_t)(c * DS + ng * 4 + q) * DI + d];
  const float Dv = Dvec[d];
  const float2* zp = &zbuf[(size_t)(c * CL) * DI + d];
  float* op = &out[(size_t)(c * CL) * DI + d];
  float2 zb[8];
#pragma unroll
  for (int j = 0; j < 8; ++j) zb[j] = zp[(size_t)j * DI];
  for (int tt = 0; tt < CL; tt += 8) {
#pragma unroll
    for (int j = 0; j < 8; ++j) {
      float dl = zb[j].x, xv = zb[j].y;
      int tn = tt + 8 + j;
      if (tn < CL) zb[j] = zp[(size_t)tn * DI];
      float du = dl * xv;
      float4 b4 = *(const float4*)&sB[tt + j][ng * 4];
      float4 c4 = *(const float4*)&sC[tt + j][ng * 4];
      float bb[4] = {b4.x, b4.y, b4.z, b4.w};
      float cc[4] = {c4.x, c4.y, c4.z, c4.w};
      float y = 0.f;
#pragma unroll
      for (int q = 0; q < 4; ++q) {
        float dA = exp2f(dl * aL[q]);
        h[q] = dA * h[q] + du * bb[q];
        y += h[q] * cc[q];
      }
      y += __shfl_xor(y, 16, 64);
      y += __shfl_xor(y, 32, 64);
      if (ng == 0) op[(size_t)(tt + j) * DI] = fmaf(xv, Dv, y);
    }
  }
}

extern "C" void kernel_launch(void* const* d_in, const int* in_sizes, int n_in,
                              void* d_out, int out_size, void* d_ws, size_t ws_size,
                              hipStream_t stream) {
  const float* x     = (const float*)d_in[0];
  const float* A_log = (const float*)d_in[1];
  const float* Dvec  = (const float*)d_in[2];
  const float* xw    = (const float*)d_in[3];
  const float* dtw   = (const float*)d_in[4];
  const float* dtb   = (const float*)d_in[5];
  float* out = (float*)d_out;

  char* ws = (char*)d_ws;
  float* part  = (float*)(ws + OFF_P);
  float* xdbl  = (float*)(ws + OFF_XDBL);
  float* hend  = (float*)(ws + OFF_HEND);
  float* aprod = (float*)(ws + OFF_APROD);
  unsigned short* wh  = (unsigned short*)(ws + OFF_WH);
  unsigned short* wl  = (unsigned short*)(ws + OFF_WL);
  unsigned short* xh  = (unsigned short*)(ws + OFF_XH);
  unsigned short* xl  = (unsigned short*)(ws + OFF_XL);
  unsigned short* xph = (unsigned short*)(ws + OFF_XPH);
  unsigned short* xpl = (unsigned short*)(ws + OFF_XPL);
  unsigned short* wxh = (unsigned short*)(ws + OFF_XWH);
  unsigned short* wxl = (unsigned short*)(ws + OFF_XWL);
  float2* zbuf = (float2*)(ws + OFF_ZB);

  k_cvt<<<5120, 256, 0, stream>>>(x, xph, xpl, L_SEQ * DI / 4);
  k_cvt<<<960, 256, 0, stream>>>(xw, wxh, wxl, NE * DI / 4);
  k_cvt<<<800, 256, 0, stream>>>(dtw, wh, wl, DI * DR / 4);
  k_xdbl_mfma2<<<dim3(3, 16, SPLITK), 256, 0, stream>>>(xph, xpl, wxh, wxl, part);
  k_xdbl_reduce<<<192, 256, 0, stream>>>(part, xdbl, xh, xl);
  k_delta_mfma2<<<dim3(40, 16), 512, 0, stream>>>(xh, xl, wh, wl, dtb, x, zbuf);

  // deterministic gate: coop attr + runtime occupancy must fit 320 co-resident blocks
  int coopAttr = 0, ncu = 0, nb = 0;
  hipDeviceGetAttribute(&coopAttr, hipDeviceAttributeCooperativeLaunch, 0);
  hipDeviceGetAttribute(&ncu, hipDeviceAttributeMultiprocessorCount, 0);
  hipOccupancyMaxActiveBlocksPerMultiprocessor(&nb, (const void*)k_scan_fused2, 512, 0);
  bool useCoop = (coopAttr != 0) && ((long)nb * ncu >= 320);

  if (useCoop) {
    void* args[] = {(void*)&zbuf, (void*)&xdbl, (void*)&A_log, (void*)&Dvec,
                    (void*)&hend, (void*)&aprod, (void*)&out};
    hipError_t ce = hipLaunchCooperativeKernel((void*)k_scan_fused2, dim3(10, NC),
                                               dim3(512), args, 0, stream);
    if (ce == hipSuccess) return;
  }
  k_scan1f<<<dim3(80, NC), 256, 0, stream>>>(zbuf, xdbl, A_log, hend, aprod);
  k_scan2f<<<320, 256, 0, stream>>>(hend, aprod);
  k_scan3f<<<dim3(80, NC), 256, 0, stream>>>(zbuf, xdbl, A_log, Dvec, hend, out);
}

// Round 13
// 120.777 us; speedup vs baseline: 1.2232x; 1.0851x over previous
//
#include <hip/hip_runtime.h>
#include <hip/hip_bf16.h>

#define L_SEQ 1024
#define DI    5120
#define DS    16
#define DR    160
#define NE    192      // DR + 2*DS
#define NC    16       // scan chunks
#define CL    64       // chunk length = L_SEQ/NC (== delta GEMM BM)
#define SPLITK 16
#define KSPLIT (DI / SPLITK)   // 320
#define BK    64
#define LOG2E 1.44269504088896340736f

// workspace layout (bytes), non-overlapping; ~95MB of ~256MB
#define OFF_P     0                    // 12,582,912
#define OFF_XDBL  12582912             //    786,432
#define OFF_WH    13369344             //  1,638,400  dtw hi
#define OFF_WL    15007744             //  1,638,400  dtw lo
#define OFF_XH    16646144             //    393,216  xdbl hi
#define OFF_XL    17039360             //    393,216  xdbl lo
#define OFF_XPH   17432576             // 10,485,760  x hi
#define OFF_XPL   27918336             // 10,485,760  x lo
#define OFF_XWH   38404096             //  1,966,080  xw hi
#define OFF_XWL   40370176             //  1,966,080  xw lo
#define OFF_ZB    42336256             // 41,943,040  (delta,x) float2
#define OFF_HEND  84279296             //  5,242,880
#define OFF_APROD 89522176             //  5,242,880

typedef short s16x8 __attribute__((ext_vector_type(8)));
typedef float f32x4 __attribute__((ext_vector_type(4)));

__device__ __forceinline__ unsigned short bf_rn(float f) {
  unsigned u = __float_as_uint(f);
  u += 0x7FFFu + ((u >> 16) & 1u);
  return (unsigned short)(u >> 16);
}
__device__ __forceinline__ void split_hilo(float f, unsigned short& h, unsigned short& l) {
  h = bf_rn(f);
  float hf = __uint_as_float(((unsigned)h) << 16);
  l = bf_rn(f - hf);
}

// ---------------- generic cvt: f32 -> bf16 hi/lo planes
__global__ __launch_bounds__(256) void k_cvt(const float* __restrict__ src,
                                             unsigned short* __restrict__ hi,
                                             unsigned short* __restrict__ lo,
                                             int n4) {
  int i = blockIdx.x * 256 + threadIdx.x;
  if (i >= n4) return;
  int i4 = i * 4;
  float4 v = *(const float4*)&src[i4];
  float f[4] = {v.x, v.y, v.z, v.w};
  ushort4 h, l;
  unsigned short hh, ll;
  split_hilo(f[0], hh, ll); h.x = hh; l.x = ll;
  split_hilo(f[1], hh, ll); h.y = hh; l.y = ll;
  split_hilo(f[2], hh, ll); h.z = hh; l.z = ll;
  split_hilo(f[3], hh, ll); h.w = hh; l.w = ll;
  *(ushort4*)&hi[i4] = h;
  *(ushort4*)&lo[i4] = l;
}

// ---------------- GEMM1 (MFMA, preconverted planes)
#define AST2 72
__global__ __launch_bounds__(256) void k_xdbl_mfma2(const unsigned short* __restrict__ xph,
                                                    const unsigned short* __restrict__ xpl,
                                                    const unsigned short* __restrict__ wxh,
                                                    const unsigned short* __restrict__ wxl,
                                                    float* __restrict__ part) {
  __shared__ unsigned short sAh[64 * AST2];
  __shared__ unsigned short sAl[64 * AST2];
  const int tid  = threadIdx.x;
  const int lane = tid & 63;
  const int w    = tid >> 6;
  const int wl_  = w >> 1;
  const int we   = w & 1;
  const int l0   = blockIdx.y * 64;
  const int e0   = blockIdx.x * 64 + we * 32;
  const int kb   = blockIdx.z * KSPLIT;
  const int rc   = lane & 15;
  const int kg   = (lane >> 4) * 8;

  f32x4 acc[2][2] = {};
  for (int k0 = 0; k0 < KSPLIT; k0 += BK) {
    __syncthreads();
    for (int idx = tid; idx < 64 * 8; idx += 256) {
      int r = idx >> 3, c8 = (idx & 7) * 8;
      *(s16x8*)&sAh[r * AST2 + c8] = *(const s16x8*)&xph[(size_t)(l0 + r) * DI + kb + k0 + c8];
      *(s16x8*)&sAl[r * AST2 + c8] = *(const s16x8*)&xpl[(size_t)(l0 + r) * DI + kb + k0 + c8];
    }
    __syncthreads();
#pragma unroll
    for (int ks = 0; ks < BK; ks += 32) {
      s16x8 ah[2], al[2], bh[2], bl[2];
#pragma unroll
      for (int mf = 0; mf < 2; ++mf) {
        int row = wl_ * 32 + mf * 16 + rc;
        ah[mf] = *(const s16x8*)&sAh[row * AST2 + ks + kg];
        al[mf] = *(const s16x8*)&sAl[row * AST2 + ks + kg];
      }
#pragma unroll
      for (int nf = 0; nf < 2; ++nf) {
        size_t e = e0 + nf * 16 + rc;
        bh[nf] = *(const s16x8*)&wxh[e * DI + kb + k0 + ks + kg];
        bl[nf] = *(const s16x8*)&wxl[e * DI + kb + k0 + ks + kg];
      }
#pragma unroll
      for (int mf = 0; mf < 2; ++mf)
#pragma unroll
        for (int nf = 0; nf < 2; ++nf) {
          acc[mf][nf] = __builtin_amdgcn_mfma_f32_16x16x32_bf16(ah[mf], bh[nf], acc[mf][nf], 0, 0, 0);
          acc[mf][nf] = __builtin_amdgcn_mfma_f32_16x16x32_bf16(ah[mf], bl[nf], acc[mf][nf], 0, 0, 0);
          acc[mf][nf] = __builtin_amdgcn_mfma_f32_16x16x32_bf16(al[mf], bh[nf], acc[mf][nf], 0, 0, 0);
        }
    }
  }
#pragma unroll
  for (int mf = 0; mf < 2; ++mf)
#pragma unroll
    for (int nf = 0; nf < 2; ++nf)
#pragma unroll
      for (int r = 0; r < 4; ++r) {
        int l = l0 + wl_ * 32 + mf * 16 + (lane >> 4) * 4 + r;
        int e = e0 + nf * 16 + rc;
        part[((size_t)blockIdx.z * L_SEQ + l) * NE + e] = acc[mf][nf][r];
      }
}

// ---------------- reduce split-K partials; emit xdbl + bf16 planes
__global__ __launch_bounds__(256) void k_xdbl_reduce(const float* __restrict__ part,
                                                     float* __restrict__ xdbl,
                                                     unsigned short* __restrict__ xh,
                                                     unsigned short* __restrict__ xl) {
  int i4 = (blockIdx.x * 256 + threadIdx.x) * 4;   // grid=192
  float4 s = {0.f, 0.f, 0.f, 0.f};
#pragma unroll
  for (int z = 0; z < SPLITK; ++z) {
    float4 p = *(const float4*)&part[(size_t)z * L_SEQ * NE + i4];
    s.x += p.x; s.y += p.y; s.z += p.z; s.w += p.w;
  }
  *(float4*)&xdbl[i4] = s;
  float f[4] = {s.x, s.y, s.z, s.w};
  ushort4 h, l;
  unsigned short hh, ll;
  split_hilo(f[0], hh, ll); h.x = hh; l.x = ll;
  split_hilo(f[1], hh, ll); h.y = hh; l.y = ll;
  split_hilo(f[2], hh, ll); h.z = hh; l.z = ll;
  split_hilo(f[3], hh, ll); h.w = hh; l.w = ll;
  *(ushort4*)&xh[i4] = h;
  *(ushort4*)&xl[i4] = l;
}

// ---------------- fused GEMM2 + scan1: delta tile -> LDS -> chunk-local scan
// grid (40, 16): blockIdx.y = chunk c (l0 = c*64), 128 d per block, 512 threads.
// LDS phases alias one 43KB buffer: [GEMM: sAh|sAl] then [scan: sDelta|sB].
#define AST 168
#define DST 129   // sDelta row stride in floats (stride-1 bank step -> conflict-free columns)
__global__ __launch_bounds__(512) void k_delta_scan1(const unsigned short* __restrict__ xh,
                                                     const unsigned short* __restrict__ xl,
                                                     const unsigned short* __restrict__ wh,
                                                     const unsigned short* __restrict__ wlo,
                                                     const float* __restrict__ dtb,
                                                     const float* __restrict__ x,
                                                     const float* __restrict__ xdbl,
                                                     const float* __restrict__ A_log,
                                                     float2* __restrict__ zbuf,
                                                     float* __restrict__ hend,
                                                     float* __restrict__ aprod) {
  __shared__ __align__(16) unsigned char smem[64 * AST * 2 * 2];   // 43008 B
  unsigned short* sAh = (unsigned short*)smem;
  unsigned short* sAl = sAh + 64 * AST;
  const int tid  = threadIdx.x;
  const int lane = tid & 63;
  const int w    = tid >> 6;
  const int wl_  = w >> 2;
  const int wd   = w & 3;
  const int c    = blockIdx.y;
  const int l0   = c * 64;
  const int d0b  = blockIdx.x * 128;
  const int d0   = d0b + wd * 32;
  const int rc   = lane & 15;
  const int kg   = (lane >> 4) * 8;

  // --- GEMM phase ---
  for (int idx = tid; idx < 64 * 20; idx += 512) {
    int r = idx / 20, c8 = (idx % 20) * 8;
    *(s16x8*)&sAh[r * AST + c8] = *(const s16x8*)&xh[(size_t)(l0 + r) * NE + c8];
    *(s16x8*)&sAl[r * AST + c8] = *(const s16x8*)&xl[(size_t)(l0 + r) * NE + c8];
  }
  __syncthreads();

  f32x4 acc[2][2] = {};
#pragma unroll
  for (int k0 = 0; k0 < DR; k0 += 32) {
    s16x8 ah[2], al[2], bh[2], bl[2];
#pragma unroll
    for (int mf = 0; mf < 2; ++mf) {
      int row = wl_ * 32 + mf * 16 + rc;
      ah[mf] = *(const s16x8*)&sAh[row * AST + k0 + kg];
      al[mf] = *(const s16x8*)&sAl[row * AST + k0 + kg];
    }
#pragma unroll
    for (int nf = 0; nf < 2; ++nf) {
      size_t d = d0 + nf * 16 + rc;
      bh[nf] = *(const s16x8*)&wh[d * DR + k0 + kg];
      bl[nf] = *(const s16x8*)&wlo[d * DR + k0 + kg];
    }
#pragma unroll
    for (int mf = 0; mf < 2; ++mf)
#pragma unroll
      for (int nf = 0; nf < 2; ++nf) {
        acc[mf][nf] = __builtin_amdgcn_mfma_f32_16x16x32_bf16(ah[mf], bh[nf], acc[mf][nf], 0, 0, 0);
        acc[mf][nf] = __builtin_amdgcn_mfma_f32_16x16x32_bf16(ah[mf], bl[nf], acc[mf][nf], 0, 0, 0);
        acc[mf][nf] = __builtin_amdgcn_mfma_f32_16x16x32_bf16(al[mf], bh[nf], acc[mf][nf], 0, 0, 0);
      }
  }
  __syncthreads();   // sAh/sAl dead; safe to repurpose LDS

  // --- epilogue: softplus -> sDelta + zbuf; stage sB ---
  float* sDelta = (float*)smem;                       // [64][DST]
  float* sB     = (float*)(smem + 64 * DST * 4);      // [64][16]
  for (int i = tid; i < 64 * 16; i += 512) {
    int t = i >> 4, n = i & 15;
    sB[i] = xdbl[(size_t)(l0 + t) * NE + DR + n];
  }
#pragma unroll
  for (int nf = 0; nf < 2; ++nf) {
    int d = d0 + nf * 16 + rc;
    int dloc = d - d0b;
    float bias = dtb[d];
#pragma unroll
    for (int mf = 0; mf < 2; ++mf)
#pragma unroll
      for (int r = 0; r < 4; ++r) {
        int lloc = wl_ * 32 + mf * 16 + (lane >> 4) * 4 + r;
        int l = l0 + lloc;
        float z = acc[mf][nf][r] + bias;
        float sp = fmaxf(z, 0.f) + __logf(1.f + __expf(-fabsf(z)));
        float xv = x[(size_t)l * DI + d];
        sDelta[lloc * DST + dloc] = sp;
        zbuf[(size_t)l * DI + d] = make_float2(sp, xv);
      }
  }
  __syncthreads();

  // --- scan phase: 512 thr = 128 d x 4 ng; dl from LDS, x from global (L2/L3-hot) ---
  const int dloc = tid & 127;
  const int ng   = tid >> 7;
  const int d    = d0b + dloc;
  float4 av = *(const float4*)&A_log[(size_t)d * DS + ng * 4];
  float aL[4] = {-__expf(av.x) * LOG2E, -__expf(av.y) * LOG2E,
                 -__expf(av.z) * LOG2E, -__expf(av.w) * LOG2E};
  float h[4] = {0.f, 0.f, 0.f, 0.f};
  float sdl = 0.f;
  const float* xp = &x[(size_t)l0 * DI + d];
  float xb[4];
#pragma unroll
  for (int j = 0; j < 4; ++j) xb[j] = xp[(size_t)j * DI];
  for (int tt = 0; tt < CL; tt += 4) {
    bool pf = (tt + 4 < CL);
#pragma unroll
    for (int j = 0; j < 4; ++j) {
      float xv = xb[j];
      if (pf) xb[j] = xp[(size_t)(tt + 4 + j) * DI];
      float dl = sDelta[(tt + j) * DST + dloc];
      float du = dl * xv;
      sdl += dl;
      float4 b4 = *(const float4*)&sB[(tt + j) * 16 + ng * 4];
      float bb[4] = {b4.x, b4.y, b4.z, b4.w};
#pragma unroll
      for (int q = 0; q < 4; ++q) {
        float dA = exp2f(dl * aL[q]);
        h[q] = dA * h[q] + du * bb[q];
      }
    }
  }
#pragma unroll
  for (int q = 0; q < 4; ++q) {
    int n = ng * 4 + q;
    hend[(size_t)(c * DS + n) * DI + d] = h[q];
    aprod[(size_t)(c * DS + n) * DI + d] = exp2f(aL[q] * sdl);
  }
}

// ---------------- scan pass 2: load-all-then-carry (in-place -> hstart)
__global__ __launch_bounds__(256) void k_scan2(float* __restrict__ hend,
                                               const float* __restrict__ aprod) {
  int i = blockIdx.x * 256 + threadIdx.x;   // 81920, grid=320
  float ap[NC], hv[NC];
#pragma unroll
  for (int c = 0; c < NC; ++c) {
    size_t idx = (size_t)c * DS * DI + i;
    ap[c] = aprod[idx];
    hv[c] = hend[idx];
  }
  float carry = 0.f;
#pragma unroll
  for (int c = 0; c < NC; ++c) {
    size_t idx = (size_t)c * DS * DI + i;
    hend[idx] = carry;
    carry = ap[c] * carry + hv[c];
  }
}

// ---------------- scan pass 3: ng-split, PF=8, float2 zbuf, emit y
__global__ __launch_bounds__(256) void k_scan3(const float2* __restrict__ zbuf,
                                               const float* __restrict__ xdbl,
                                               const float* __restrict__ A_log,
                                               const float* __restrict__ Dvec,
                                               const float* __restrict__ hstart,
                                               float* __restrict__ out) {
  const int lane = threadIdx.x & 63;
  const int w    = threadIdx.x >> 6;
  const int d    = blockIdx.x * 64 + w * 16 + (lane & 15);
  const int ng   = lane >> 4;
  const int c    = blockIdx.y;
  __shared__ __align__(16) float sB[CL][DS];
  __shared__ __align__(16) float sC[CL][DS];
  for (int i = threadIdx.x; i < CL * DS; i += 256) {
    int t = i >> 4, n = i & 15;
    sB[t][n] = xdbl[(size_t)(c * CL + t) * NE + DR + n];
    sC[t][n] = xdbl[(size_t)(c * CL + t) * NE + DR + DS + n];
  }
  __syncthreads();
  float4 av = *(const float4*)&A_log[(size_t)d * DS + ng * 4];
  float aL[4] = {-__expf(av.x) * LOG2E, -__expf(av.y) * LOG2E,
                 -__expf(av.z) * LOG2E, -__expf(av.w) * LOG2E};
  float h[4];
#pragma unroll
  for (int q = 0; q < 4; ++q)
    h[q] = hstart[(size_t)(c * DS + ng * 4 + q) * DI + d];
  const float Dv = Dvec[d];
  const float2* zp = &zbuf[(size_t)(c * CL) * DI + d];
  float* op = &out[(size_t)(c * CL) * DI + d];
  float2 zb[8];
#pragma unroll
  for (int j = 0; j < 8; ++j) zb[j] = zp[(size_t)j * DI];
  for (int tt = 0; tt < CL; tt += 8) {
#pragma unroll
    for (int j = 0; j < 8; ++j) {
      float dl = zb[j].x, xv = zb[j].y;
      int tn = tt + 8 + j;
      if (tn < CL) zb[j] = zp[(size_t)tn * DI];
      float du = dl * xv;
      float4 b4 = *(const float4*)&sB[tt + j][ng * 4];
      float4 c4 = *(const float4*)&sC[tt + j][ng * 4];
      float bb[4] = {b4.x, b4.y, b4.z, b4.w};
      float cc[4] = {c4.x, c4.y, c4.z, c4.w};
      float y = 0.f;
#pragma unroll
      for (int q = 0; q < 4; ++q) {
        float dA = exp2f(dl * aL[q]);
        h[q] = dA * h[q] + du * bb[q];
        y += h[q] * cc[q];
      }
      y += __shfl_xor(y, 16, 64);
      y += __shfl_xor(y, 32, 64);
      if (ng == 0) op[(size_t)(tt + j) * DI] = fmaf(xv, Dv, y);
    }
  }
}

extern "C" void kernel_launch(void* const* d_in, const int* in_sizes, int n_in,
                              void* d_out, int out_size, void* d_ws, size_t ws_size,
                              hipStream_t stream) {
  const float* x     = (const float*)d_in[0];
  const float* A_log = (const float*)d_in[1];
  const float* Dvec  = (const float*)d_in[2];
  const float* xw    = (const float*)d_in[3];
  const float* dtw   = (const float*)d_in[4];
  const float* dtb   = (const float*)d_in[5];
  float* out = (float*)d_out;

  char* ws = (char*)d_ws;
  float* part  = (float*)(ws + OFF_P);
  float* xdbl  = (float*)(ws + OFF_XDBL);
  float* hend  = (float*)(ws + OFF_HEND);
  float* aprod = (float*)(ws + OFF_APROD);
  unsigned short* wh  = (unsigned short*)(ws + OFF_WH);
  unsigned short* wl  = (unsigned short*)(ws + OFF_WL);
  unsigned short* xh  = (unsigned short*)(ws + OFF_XH);
  unsigned short* xl  = (unsigned short*)(ws + OFF_XL);
  unsigned short* xph = (unsigned short*)(ws + OFF_XPH);
  unsigned short* xpl = (unsigned short*)(ws + OFF_XPL);
  unsigned short* wxh = (unsigned short*)(ws + OFF_XWH);
  unsigned short* wxl = (unsigned short*)(ws + OFF_XWL);
  float2* zbuf = (float2*)(ws + OFF_ZB);

  k_cvt<<<5120, 256, 0, stream>>>(x, xph, xpl, L_SEQ * DI / 4);
  k_cvt<<<960, 256, 0, stream>>>(xw, wxh, wxl, NE * DI / 4);
  k_cvt<<<800, 256, 0, stream>>>(dtw, wh, wl, DI * DR / 4);
  k_xdbl_mfma2<<<dim3(3, 16, SPLITK), 256, 0, stream>>>(xph, xpl, wxh, wxl, part);
  k_xdbl_reduce<<<192, 256, 0, stream>>>(part, xdbl, xh, xl);
  k_delta_scan1<<<dim3(40, 16), 512, 0, stream>>>(xh, xl, wh, wl, dtb, x, xdbl,
                                                  A_log, zbuf, hend, aprod);
  k_scan2<<<320, 256, 0, stream>>>(hend, aprod);
  k_scan3<<<dim3(80, 16), 256, 0, stream>>>(zbuf, xdbl, A_log, Dvec, hend, out);
}